// Round 7
// baseline (530.080 us; speedup 1.0000x reference)
//
#include <hip/hip_runtime.h>
#include <hip/hip_bf16.h>
#include <cstdint>

typedef short short8 __attribute__((ext_vector_type(8)));
typedef __bf16 bf16x8 __attribute__((ext_vector_type(8)));
typedef float float4v __attribute__((ext_vector_type(4)));
typedef float float16v __attribute__((ext_vector_type(16)));

#define NKV 8
#define G 8
#define D 64
#define NH 64
#define BB 2
#define S 1024
#define H 4096
#define MROWS (BB*S)         // 2048
#define NQKV (H + 2*NKV*D)   // 5120

__device__ __forceinline__ unsigned short f2b(float f) {
    union { float f; uint32_t u; } v; v.f = f;
    uint32_t u = v.u;
    uint32_t r = (u + 0x7FFFu + ((u >> 16) & 1u)) >> 16;
    return (unsigned short)r;
}
__device__ __forceinline__ float b2f(unsigned short b) {
    union { float f; uint32_t u; } v; v.u = ((uint32_t)b) << 16;
    return v.f;
}

__device__ __forceinline__ void gload_lds16(const unsigned short* g, unsigned short* l) {
    __builtin_amdgcn_global_load_lds(
        (const __attribute__((address_space(1))) uint32_t*)g,
        (__attribute__((address_space(3))) uint32_t*)l, 16, 0, 0);
}

// ---------------- fused fp32 -> bf16 conversion for all 5 tensors ----------------
__global__ void cvt_all(const float* __restrict__ hs, const float* __restrict__ wq,
                        const float* __restrict__ wk, const float* __restrict__ wv,
                        const float* __restrict__ wd,
                        unsigned short* __restrict__ hs_b, unsigned short* __restrict__ wqkv_b,
                        unsigned short* __restrict__ wd_b) {
    const size_t N0 = (size_t)MROWS * H;      // 8388608  hs
    const size_t N1 = (size_t)H * H;          // 16777216 wq
    const size_t N2 = (size_t)512 * H;        // 2097152  wk
    const size_t N3 = (size_t)512 * H;        // 2097152  wv
    const size_t N4 = (size_t)H * H;          // 16777216 wd
    const size_t total4 = (N0 + N1 + N2 + N3 + N4) / 4;
    size_t i = (size_t)blockIdx.x * blockDim.x + threadIdx.x;
    const size_t stride = (size_t)gridDim.x * blockDim.x;
    for (; i < total4; i += stride) {
        size_t e = i * 4;
        const float* s; unsigned short* d;
        if (e < N0)                { s = hs + e;                  d = hs_b + e; }
        else if (e < N0+N1)        { s = wq + (e-N0);             d = wqkv_b + (e-N0); }
        else if (e < N0+N1+N2)     { s = wk + (e-N0-N1);          d = wqkv_b + N1 + (e-N0-N1); }
        else if (e < N0+N1+N2+N3)  { s = wv + (e-N0-N1-N2);       d = wqkv_b + N1+N2 + (e-N0-N1-N2); }
        else                       { s = wd + (e-N0-N1-N2-N3);    d = wd_b + (e-N0-N1-N2-N3); }
        float4 f = *(const float4*)s;
        ushort4 o;
        o.x = f2b(f.x); o.y = f2b(f.y); o.z = f2b(f.z); o.w = f2b(f.w);
        *(ushort4*)d = o;
    }
}

// ---------------- NT GEMM: C[M,N] = A[M,K] * W[N,K]^T ----------------
// Proven structure: 128x128 tile, BK=32, 4 waves (2x2 of 64x64),
// mfma_f32_32x32x16_bf16 (2x2 of 32x32 per wave), global_load_lds width=16 staging,
// XOR chunk swizzle, pointer-bumped K loop.
// MODE 0: plain fp32 C store (GEMM2).
// MODE 1: fused QKV epilogue (GEMM1): per-wave 64-col window == one head's d range.
//   RoPE partner of acc[mg][0][reg] (d=n32) is acc[mg][1][reg] (d=n32+32): same lane,
//   same reg -> no shuffles. Q cols [0,4096) -> qa scaled by SC2 = 0.125*log2(e)
//   (folds attention's score scale; RoPE is linear so scale commutes);
//   K cols [4096,4608) -> ka; V cols [4608,5120) -> vt[d][s] via in-LDS transpose.
template <int MODE>
__global__ __launch_bounds__(256) void gemm_nt(
    const unsigned short* __restrict__ A, const unsigned short* __restrict__ W,
    void* __restrict__ Cv, int M, int N, int K,
    const float* __restrict__ cosb, const float* __restrict__ sinb,
    unsigned short* __restrict__ qa, unsigned short* __restrict__ ka,
    unsigned short* __restrict__ vt) {
    __shared__ unsigned short sh[17408];  // As | Bs; reused as 128x136 V-transpose tile
    unsigned short* As = sh;
    unsigned short* Bs = sh + 4096;
    const int bm = blockIdx.y * 128, bn = blockIdx.x * 128;
    const int tid = threadIdx.x;
    const int w = tid >> 6, lane = tid & 63;
    const int n32 = lane & 31, khalf = lane >> 5;
    const int wm = (w & 1) * 64, wn = (w >> 1) * 64;

    const int r0 = tid >> 2;
    const int c0 = (tid & 3) ^ ((r0 >> 2) & 3);
    const unsigned short* pA0 = A + (size_t)(bm + r0) * K + c0 * 8;
    const unsigned short* pA1 = A + (size_t)(bm + r0 + 64) * K + c0 * 8;
    const unsigned short* pW0 = W + (size_t)(bn + r0) * K + c0 * 8;
    const unsigned short* pW1 = W + (size_t)(bn + r0 + 64) * K + c0 * 8;
    unsigned short* Asl0 = As + tid * 8;
    unsigned short* Asl1 = As + 2048 + tid * 8;
    unsigned short* Bsl0 = Bs + tid * 8;
    unsigned short* Bsl1 = Bs + 2048 + tid * 8;

    const unsigned short* aP[2][2];
    const unsigned short* bP[2][2];
#pragma unroll
    for (int g = 0; g < 2; g++)
#pragma unroll
        for (int s = 0; s < 2; s++) {
            int cp = ((s << 1) | khalf) ^ ((n32 >> 2) & 3);
            aP[g][s] = &As[(wm + g * 32 + n32) * 32 + cp * 8];
            bP[g][s] = &Bs[(wn + g * 32 + n32) * 32 + cp * 8];
        }

    float16v acc[2][2] = {};

    const int iters = K >> 5;
    for (int it = 0; it < iters; ++it) {
        __syncthreads();
        gload_lds16(pA0, Asl0);
        gload_lds16(pA1, Asl1);
        gload_lds16(pW0, Bsl0);
        gload_lds16(pW1, Bsl1);
        pA0 += 32; pA1 += 32; pW0 += 32; pW1 += 32;
        __syncthreads();
        bf16x8 af[2][2], bf[2][2];
#pragma unroll
        for (int g = 0; g < 2; g++)
#pragma unroll
            for (int s = 0; s < 2; s++) {
                af[g][s] = *(const bf16x8*)aP[g][s];
                bf[g][s] = *(const bf16x8*)bP[g][s];
            }
#pragma unroll
        for (int s = 0; s < 2; s++)
#pragma unroll
            for (int mg = 0; mg < 2; mg++)
#pragma unroll
                for (int ng = 0; ng < 2; ng++)
                    acc[mg][ng] = __builtin_amdgcn_mfma_f32_32x32x16_bf16(
                        af[mg][s], bf[ng][s], acc[mg][ng], 0, 0, 0);
    }

    // C/D layout (verified): col = lane&31, row = (reg&3) + 8*(reg>>2) + 4*(lane>>5)
    if (MODE == 0) {
#pragma unroll
        for (int mg = 0; mg < 2; mg++) {
#pragma unroll
            for (int ng = 0; ng < 2; ng++) {
                int gcol = bn + wn + ng * 32 + n32;
#pragma unroll
                for (int reg = 0; reg < 16; reg++) {
                    int grow = bm + wm + mg * 32 + (reg & 3) + 8 * (reg >> 2) + 4 * khalf;
                    ((float*)Cv)[(size_t)grow * N + gcol] = acc[mg][ng][reg];
                }
            }
        }
    } else {
        const int colbase = bn + wn;  // 64-aligned: one head's d-range per wave
        const float SCQ = 0.125f * 1.44269504089f;
        if (bn < H + 512) {
            // Q or K with fused RoPE (block-uniform branch; per-wave stores coalesced)
#pragma unroll
            for (int mg = 0; mg < 2; mg++) {
#pragma unroll
                for (int reg = 0; reg < 16; reg++) {
                    int grow = bm + wm + mg * 32 + (reg & 3) + 8 * (reg >> 2) + 4 * khalf;
                    int s = grow & 1023, b = grow >> 10;
                    float x0 = acc[mg][0][reg], x1 = acc[mg][1][reg];
                    float c0  = cosb[s * 64 + n32],      sn0 = sinb[s * 64 + n32];
                    float c1  = cosb[s * 64 + 32 + n32], sn1 = sinb[s * 64 + 32 + n32];
                    float y0 = x0 * c0 - x1 * sn0;
                    float y1 = x1 * c1 + x0 * sn1;
                    unsigned short* dp;
                    if (bn < H) {
                        y0 *= SCQ; y1 *= SCQ;   // fold score scale into Q
                        dp = qa + (size_t)(b * 64 + (colbase >> 6)) * (S * D) + s * 64 + n32;
                    } else {
                        dp = ka + (size_t)(b * 8 + ((colbase - H) >> 6)) * (S * D) + s * 64 + n32;
                    }
                    dp[0] = f2b(y0); dp[32] = f2b(y1);
                }
            }
        } else {
            // V block: cooperative 128x128 transpose via LDS, stores coalesced along s
            __syncthreads();   // everyone done with As/Bs (aliased by sh)
#pragma unroll
            for (int mg = 0; mg < 2; mg++)
#pragma unroll
                for (int ng = 0; ng < 2; ng++)
#pragma unroll
                    for (int reg = 0; reg < 16; reg++) {
                        int cl = wn + ng * 32 + n32;   // local col = V's d-within-block
                        int rl = wm + mg * 32 + (reg & 3) + 8 * (reg >> 2) + 4 * khalf;
                        sh[cl * 136 + rl] = f2b(acc[mg][ng][reg]);
                    }
            __syncthreads();
            {
                const int bb = bm >> 10, s0 = bm & 1023;
                const int kv0 = (bn - (H + 512)) >> 6;
                const int cl = tid >> 1, shalf = (tid & 1) * 64;
                const int kv = kv0 + (cl >> 6), dd = cl & 63;
                unsigned short* dstp = vt + (size_t)(bb * 8 + kv) * (D * S)
                                          + (size_t)dd * S + s0 + shalf;
                const unsigned short* srcp = sh + cl * 136 + shalf;
#pragma unroll
                for (int j = 0; j < 8; j++)
                    *(short8*)(dstp + j * 8) = *(const short8*)(srcp + j * 8);
            }
        }
    }
}

// ---------------- Flash attention, pair-balanced, ONE query head per block ----------------
// Round-7 change: head-pair split into separate blocks -> grid (8,128) = 1024 uniform
// blocks (17 K-tiles each) = 4 blocks/CU = 4 waves/SIMD (was 2). Attn is latency-bound
// (round-6 VALU cut was neutral): 2x TLP attacks the load-wait directly. K/V L2-resident
// so the 2x load issue is free in BW. V loads issued AFTER the QK cluster so bk's 32
// VGPR die before bv's 32 live (keeps VGPR ~<=128 for 16 waves/CU residency); V's wait
// is covered by the exp2/Ps softmax section.
// Fixed-max softmax (scores bounded, exp2 can't overflow), diagonal-only masking,
// score scale pre-folded into qa by GEMM1.
__global__ __launch_bounds__(256) void attn_kernel(
    const unsigned short* __restrict__ qa, const unsigned short* __restrict__ ka,
    const unsigned short* __restrict__ vt, unsigned short* __restrict__ out) {
    __shared__ unsigned short Ps[4 * 16 * 72];   // wave-private P round-trip only
    const int p = blockIdx.x;
    const int yy = blockIdx.y;
    const int b = yy >> 6, kvh = (yy >> 3) & 7, g = yy & 7;
    const int h0 = b * 64 + kvh * 8 + g;
    const int tid = threadIdx.x, w = tid >> 6, lane = tid & 63;
    const int col = lane & 15, quad = lane >> 4;
    const unsigned short* Kg = ka + (size_t)(b * NKV + kvh) * (S * D);
    const unsigned short* Vg = vt + (size_t)(b * NKV + kvh) * (D * S);
    float4v zero4 = {0.f, 0.f, 0.f, 0.f};

#pragma unroll
    for (int part = 0; part < 2; part++) {
        const int qt = part ? (15 - p) : p;
        const int qb = qt * 64;

        bf16x8 aq[2];
#pragma unroll
        for (int c = 0; c < 2; c++)
            aq[c] = *(const bf16x8*)&qa[(size_t)h0 * (S * D) + (size_t)qb * D
                                        + (w * 16 + col) * 64 + c * 32 + quad * 8];

        float l_run[4] = {0.f, 0.f, 0.f, 0.f};
        float4v o_acc[4];
#pragma unroll
        for (int dg = 0; dg < 4; dg++) o_acc[dg] = zero4;

        for (int kt = 0; kt <= qt; kt++) {
            const int kb = kt * 64;
            // K fragments (consumed by QK; registers freed before V arrives)
            bf16x8 bk[4][2];
#pragma unroll
            for (int n16 = 0; n16 < 4; n16++) {
                const unsigned short* kr = &Kg[(size_t)(kb + n16 * 16 + col) * 64 + quad * 8];
                bk[n16][0] = *(const bf16x8*)kr;
                bk[n16][1] = *(const bf16x8*)(kr + 32);
            }
            float4v sc[4];
            __builtin_amdgcn_s_setprio(1);
#pragma unroll
            for (int n16 = 0; n16 < 4; n16++) {
                float4v a = __builtin_amdgcn_mfma_f32_16x16x32_bf16(aq[0], bk[n16][0], zero4, 0, 0, 0);
                sc[n16] = __builtin_amdgcn_mfma_f32_16x16x32_bf16(aq[1], bk[n16][1], a, 0, 0, 0);
            }
            __builtin_amdgcn_s_setprio(0);
            // V fragments issued here: latency covered by mask/exp2/Ps below
            bf16x8 bv[4][2];
#pragma unroll
            for (int dg = 0; dg < 4; dg++) {
                const unsigned short* vr = &Vg[(size_t)(dg * 16 + col) * S + kb + quad * 8];
                bv[dg][0] = *(const bf16x8*)vr;
                bv[dg][1] = *(const bf16x8*)(vr + 32);
            }
            if (kt == qt) {
                // diagonal tile only: mask key_local > qrow_local
#pragma unroll
                for (int n16 = 0; n16 < 4; n16++) {
                    int keyl = n16 * 16 + col;
#pragma unroll
                    for (int r = 0; r < 4; r++) {
                        int qrl = w * 16 + quad * 4 + r;
                        sc[n16][r] = (keyl <= qrl) ? sc[n16][r] : -1e30f;
                    }
                }
            }
#pragma unroll
            for (int n16 = 0; n16 < 4; n16++)
#pragma unroll
                for (int r = 0; r < 4; r++) {
                    float pr = __builtin_amdgcn_exp2f(sc[n16][r]);
                    sc[n16][r] = pr;
                    l_run[r] += pr;
                    Ps[w * 1152 + (quad * 4 + r) * 72 + n16 * 16 + col] = f2b(pr);
                }
            bf16x8 ap[2];
#pragma unroll
            for (int c = 0; c < 2; c++)
                ap[c] = *(const bf16x8*)&Ps[w * 1152 + col * 72 + c * 32 + quad * 8];
            __builtin_amdgcn_s_setprio(1);
#pragma unroll
            for (int dg = 0; dg < 4; dg++) {
                float4v t = __builtin_amdgcn_mfma_f32_16x16x32_bf16(ap[0], bv[dg][0], o_acc[dg], 0, 0, 0);
                o_acc[dg] = __builtin_amdgcn_mfma_f32_16x16x32_bf16(ap[1], bv[dg][1], t, 0, 0, 0);
            }
            __builtin_amdgcn_s_setprio(0);
        }
        {
            const int hcol = (h0 & 63) * 64;
#pragma unroll
            for (int r = 0; r < 4; r++) {
                float lsum = l_run[r];
#pragma unroll
                for (int off = 1; off < 16; off <<= 1) lsum += __shfl_xor(lsum, off);
                float inv = 1.f / lsum;
                int grow = b * S + qb + w * 16 + quad * 4 + r;
#pragma unroll
                for (int dg = 0; dg < 4; dg++)
                    out[(size_t)grow * H + hcol + dg * 16 + col] = f2b(o_acc[dg][r] * inv);
            }
        }
    }
}

extern "C" void kernel_launch(void* const* d_in, const int* in_sizes, int n_in,
                              void* d_out, int out_size, void* d_ws, size_t ws_size,
                              hipStream_t stream) {
    const float* hs   = (const float*)d_in[0];
    // d_in[1] alibi, d_in[2] attention_mask: unused by reference (zeros)
    const float* cosb = (const float*)d_in[3];
    const float* sinb = (const float*)d_in[4];
    const float* wq   = (const float*)d_in[5];
    const float* wk   = (const float*)d_in[6];
    const float* wv   = (const float*)d_in[7];
    const float* wd   = (const float*)d_in[8];

    char* p = (char*)d_ws;
    auto alloc = [&](size_t bytes) { char* r = p; p += (bytes + 255) & ~(size_t)255; return r; };
    unsigned short* wqkv_b = (unsigned short*)alloc((size_t)NQKV * H * 2);
    unsigned short* wd_b   = (unsigned short*)alloc((size_t)H * H * 2);
    unsigned short* qa     = (unsigned short*)alloc((size_t)BB * NH * S * D * 2);
    unsigned short* ka     = (unsigned short*)alloc((size_t)BB * NKV * S * D * 2);
    unsigned short* vt     = (unsigned short*)alloc((size_t)BB * NKV * S * D * 2);
    unsigned short* hs_b   = (unsigned short*)alloc((size_t)MROWS * H * 2);
    unsigned short* ao     = hs_b;  // alias: hs_b consumed by GEMM1 before attn writes ao

    cvt_all<<<4096, 256, 0, stream>>>(hs, wq, wk, wv, wd, hs_b, wqkv_b, wd_b);

    // GEMM1 with fused RoPE+scatter epilogue (writes qa/ka/vt directly)
    gemm_nt<1><<<dim3(NQKV / 128, MROWS / 128), 256, 0, stream>>>(
        hs_b, wqkv_b, nullptr, MROWS, NQKV, H, cosb, sinb, qa, ka, vt);
    attn_kernel<<<dim3(8, 128), 256, 0, stream>>>(qa, ka, vt, ao);
    gemm_nt<0><<<dim3(H / 128, MROWS / 128), 256, 0, stream>>>(
        ao, wd_b, d_out, MROWS, H, H, nullptr, nullptr, nullptr, nullptr, nullptr);
}

// Round 8
// 473.249 us; speedup vs baseline: 1.1201x; 1.1201x over previous
//
#include <hip/hip_runtime.h>
#include <hip/hip_bf16.h>
#include <cstdint>

typedef short short8 __attribute__((ext_vector_type(8)));
typedef __bf16 bf16x8 __attribute__((ext_vector_type(8)));
typedef float float4v __attribute__((ext_vector_type(4)));
typedef float float16v __attribute__((ext_vector_type(16)));

#define NKV 8
#define G 8
#define D 64
#define NH 64
#define BB 2
#define S 1024
#define H 4096
#define MROWS (BB*S)         // 2048
#define NQKV (H + 2*NKV*D)   // 5120

__device__ __forceinline__ unsigned short f2b(float f) {
    union { float f; uint32_t u; } v; v.f = f;
    uint32_t u = v.u;
    uint32_t r = (u + 0x7FFFu + ((u >> 16) & 1u)) >> 16;
    return (unsigned short)r;
}
__device__ __forceinline__ float b2f(unsigned short b) {
    union { float f; uint32_t u; } v; v.u = ((uint32_t)b) << 16;
    return v.f;
}
// native RNE bf16 cast (compiler emits v_cvt_*_bf16; same rounding as f2b, fewer VALU ops)
__device__ __forceinline__ unsigned short f2b_n(float f) {
    union { __bf16 h; unsigned short u; } v; v.h = (__bf16)f;
    return v.u;
}

__device__ __forceinline__ void gload_lds16(const unsigned short* g, unsigned short* l) {
    __builtin_amdgcn_global_load_lds(
        (const __attribute__((address_space(1))) uint32_t*)g,
        (__attribute__((address_space(3))) uint32_t*)l, 16, 0, 0);
}

// ---------------- fused fp32 -> bf16 conversion for all 5 tensors ----------------
__global__ void cvt_all(const float* __restrict__ hs, const float* __restrict__ wq,
                        const float* __restrict__ wk, const float* __restrict__ wv,
                        const float* __restrict__ wd,
                        unsigned short* __restrict__ hs_b, unsigned short* __restrict__ wqkv_b,
                        unsigned short* __restrict__ wd_b) {
    const size_t N0 = (size_t)MROWS * H;      // 8388608  hs
    const size_t N1 = (size_t)H * H;          // 16777216 wq
    const size_t N2 = (size_t)512 * H;        // 2097152  wk
    const size_t N3 = (size_t)512 * H;        // 2097152  wv
    const size_t N4 = (size_t)H * H;          // 16777216 wd
    const size_t total4 = (N0 + N1 + N2 + N3 + N4) / 4;
    size_t i = (size_t)blockIdx.x * blockDim.x + threadIdx.x;
    const size_t stride = (size_t)gridDim.x * blockDim.x;
    for (; i < total4; i += stride) {
        size_t e = i * 4;
        const float* s; unsigned short* d;
        if (e < N0)                { s = hs + e;                  d = hs_b + e; }
        else if (e < N0+N1)        { s = wq + (e-N0);             d = wqkv_b + (e-N0); }
        else if (e < N0+N1+N2)     { s = wk + (e-N0-N1);          d = wqkv_b + N1 + (e-N0-N1); }
        else if (e < N0+N1+N2+N3)  { s = wv + (e-N0-N1-N2);       d = wqkv_b + N1+N2 + (e-N0-N1-N2); }
        else                       { s = wd + (e-N0-N1-N2-N3);    d = wd_b + (e-N0-N1-N2-N3); }
        float4 f = *(const float4*)s;
        ushort4 o;
        o.x = f2b(f.x); o.y = f2b(f.y); o.z = f2b(f.z); o.w = f2b(f.w);
        *(ushort4*)d = o;
    }
}

// ---------------- NT GEMM: C[M,N] = A[M,K] * W[N,K]^T ----------------
// Proven structure: 128x128 tile, BK=32, 4 waves (2x2 of 64x64),
// mfma_f32_32x32x16_bf16 (2x2 of 32x32 per wave), global_load_lds width=16 staging,
// XOR chunk swizzle, pointer-bumped K loop.
// MODE 0: plain fp32 C store (GEMM2).
// MODE 1: fused QKV epilogue (GEMM1): per-wave 64-col window == one head's d range.
//   RoPE partner of acc[mg][0][reg] (d=n32) is acc[mg][1][reg] (d=n32+32): same lane,
//   same reg -> no shuffles. Q cols [0,4096) -> qa scaled by SC2 = 0.125*log2(e)
//   (folds attention's score scale; RoPE is linear so scale commutes);
//   K cols [4096,4608) -> ka; V cols [4608,5120) -> vt[d][s] via in-LDS transpose.
template <int MODE>
__global__ __launch_bounds__(256) void gemm_nt(
    const unsigned short* __restrict__ A, const unsigned short* __restrict__ W,
    void* __restrict__ Cv, int M, int N, int K,
    const float* __restrict__ cosb, const float* __restrict__ sinb,
    unsigned short* __restrict__ qa, unsigned short* __restrict__ ka,
    unsigned short* __restrict__ vt) {
    __shared__ unsigned short sh[17408];  // As | Bs; reused as 128x136 V-transpose tile
    unsigned short* As = sh;
    unsigned short* Bs = sh + 4096;
    const int bm = blockIdx.y * 128, bn = blockIdx.x * 128;
    const int tid = threadIdx.x;
    const int w = tid >> 6, lane = tid & 63;
    const int n32 = lane & 31, khalf = lane >> 5;
    const int wm = (w & 1) * 64, wn = (w >> 1) * 64;

    const int r0 = tid >> 2;
    const int c0 = (tid & 3) ^ ((r0 >> 2) & 3);
    const unsigned short* pA0 = A + (size_t)(bm + r0) * K + c0 * 8;
    const unsigned short* pA1 = A + (size_t)(bm + r0 + 64) * K + c0 * 8;
    const unsigned short* pW0 = W + (size_t)(bn + r0) * K + c0 * 8;
    const unsigned short* pW1 = W + (size_t)(bn + r0 + 64) * K + c0 * 8;
    unsigned short* Asl0 = As + tid * 8;
    unsigned short* Asl1 = As + 2048 + tid * 8;
    unsigned short* Bsl0 = Bs + tid * 8;
    unsigned short* Bsl1 = Bs + 2048 + tid * 8;

    const unsigned short* aP[2][2];
    const unsigned short* bP[2][2];
#pragma unroll
    for (int g = 0; g < 2; g++)
#pragma unroll
        for (int s = 0; s < 2; s++) {
            int cp = ((s << 1) | khalf) ^ ((n32 >> 2) & 3);
            aP[g][s] = &As[(wm + g * 32 + n32) * 32 + cp * 8];
            bP[g][s] = &Bs[(wn + g * 32 + n32) * 32 + cp * 8];
        }

    float16v acc[2][2] = {};

    const int iters = K >> 5;
    for (int it = 0; it < iters; ++it) {
        __syncthreads();
        gload_lds16(pA0, Asl0);
        gload_lds16(pA1, Asl1);
        gload_lds16(pW0, Bsl0);
        gload_lds16(pW1, Bsl1);
        pA0 += 32; pA1 += 32; pW0 += 32; pW1 += 32;
        __syncthreads();
        bf16x8 af[2][2], bf[2][2];
#pragma unroll
        for (int g = 0; g < 2; g++)
#pragma unroll
            for (int s = 0; s < 2; s++) {
                af[g][s] = *(const bf16x8*)aP[g][s];
                bf[g][s] = *(const bf16x8*)bP[g][s];
            }
#pragma unroll
        for (int s = 0; s < 2; s++)
#pragma unroll
            for (int mg = 0; mg < 2; mg++)
#pragma unroll
                for (int ng = 0; ng < 2; ng++)
                    acc[mg][ng] = __builtin_amdgcn_mfma_f32_32x32x16_bf16(
                        af[mg][s], bf[ng][s], acc[mg][ng], 0, 0, 0);
    }

    // C/D layout (verified): col = lane&31, row = (reg&3) + 8*(reg>>2) + 4*(lane>>5)
    if (MODE == 0) {
#pragma unroll
        for (int mg = 0; mg < 2; mg++) {
#pragma unroll
            for (int ng = 0; ng < 2; ng++) {
                int gcol = bn + wn + ng * 32 + n32;
#pragma unroll
                for (int reg = 0; reg < 16; reg++) {
                    int grow = bm + wm + mg * 32 + (reg & 3) + 8 * (reg >> 2) + 4 * khalf;
                    ((float*)Cv)[(size_t)grow * N + gcol] = acc[mg][ng][reg];
                }
            }
        }
    } else {
        const int colbase = bn + wn;  // 64-aligned: one head's d-range per wave
        const float SCQ = 0.125f * 1.44269504089f;
        if (bn < H + 512) {
            // Q or K with fused RoPE (block-uniform branch; per-wave stores coalesced)
#pragma unroll
            for (int mg = 0; mg < 2; mg++) {
#pragma unroll
                for (int reg = 0; reg < 16; reg++) {
                    int grow = bm + wm + mg * 32 + (reg & 3) + 8 * (reg >> 2) + 4 * khalf;
                    int s = grow & 1023, b = grow >> 10;
                    float x0 = acc[mg][0][reg], x1 = acc[mg][1][reg];
                    float c0  = cosb[s * 64 + n32],      sn0 = sinb[s * 64 + n32];
                    float c1  = cosb[s * 64 + 32 + n32], sn1 = sinb[s * 64 + 32 + n32];
                    float y0 = x0 * c0 - x1 * sn0;
                    float y1 = x1 * c1 + x0 * sn1;
                    unsigned short* dp;
                    if (bn < H) {
                        y0 *= SCQ; y1 *= SCQ;   // fold score scale into Q
                        dp = qa + (size_t)(b * 64 + (colbase >> 6)) * (S * D) + s * 64 + n32;
                    } else {
                        dp = ka + (size_t)(b * 8 + ((colbase - H) >> 6)) * (S * D) + s * 64 + n32;
                    }
                    dp[0] = f2b(y0); dp[32] = f2b(y1);
                }
            }
        } else {
            // V block: cooperative 128x128 transpose via LDS, stores coalesced along s
            __syncthreads();   // everyone done with As/Bs (aliased by sh)
#pragma unroll
            for (int mg = 0; mg < 2; mg++)
#pragma unroll
                for (int ng = 0; ng < 2; ng++)
#pragma unroll
                    for (int reg = 0; reg < 16; reg++) {
                        int cl = wn + ng * 32 + n32;   // local col = V's d-within-block
                        int rl = wm + mg * 32 + (reg & 3) + 8 * (reg >> 2) + 4 * khalf;
                        sh[cl * 136 + rl] = f2b(acc[mg][ng][reg]);
                    }
            __syncthreads();
            {
                const int bb = bm >> 10, s0 = bm & 1023;
                const int kv0 = (bn - (H + 512)) >> 6;
                const int cl = tid >> 1, shalf = (tid & 1) * 64;
                const int kv = kv0 + (cl >> 6), dd = cl & 63;
                unsigned short* dstp = vt + (size_t)(bb * 8 + kv) * (D * S)
                                          + (size_t)dd * S + s0 + shalf;
                const unsigned short* srcp = sh + cl * 136 + shalf;
#pragma unroll
                for (int j = 0; j < 8; j++)
                    *(short8*)(dstp + j * 8) = *(const short8*)(srcp + j * 8);
            }
        }
    }
}

// ---------------- Flash attention: kt-outer, 4 chains per staged tile ----------------
// Round-8 restructure. Block = (q-pair p, b, kvh, head-pair): grid (8, 64), 4 waves.
// kt loops OUTER (0..15-p); K/V fragments loaded ONCE per kt into registers and
// consumed by up to 4 independent chains (2 q-parts x 2 heads). This raises work
// per loaded tile 4x and gives the load-wait 4 independent MFMA+VALU chains to
// hide under (round-7 counters: all pipes <20% busy -> latency-bound, redundant
// per-wave K/V loads the cost). Loads per block drop 17 -> 16-p. No barriers.
// Fixed-max softmax, diagonal-only masking, scale pre-folded into qa.
__global__ __launch_bounds__(256, 2) void attn_kernel(
    const unsigned short* __restrict__ qa, const unsigned short* __restrict__ ka,
    const unsigned short* __restrict__ vt, unsigned short* __restrict__ out) {
    __shared__ unsigned short Ps[4 * 16 * 72];   // wave-private P round-trip only
    const int p = blockIdx.x;
    const int yy = blockIdx.y;
    const int b = yy >> 5, kvh = (yy >> 2) & 7, gp = yy & 3;
    const int h0 = b * 64 + kvh * 8 + gp * 2;
    const int tid = threadIdx.x, w = tid >> 6, lane = tid & 63;
    const int col = lane & 15, quad = lane >> 4;
    const unsigned short* Kg = ka + (size_t)(b * NKV + kvh) * (S * D);
    const unsigned short* Vg = vt + (size_t)(b * NKV + kvh) * (D * S);
    float4v zero4 = {0.f, 0.f, 0.f, 0.f};

    const int qt0 = p, qt1 = 15 - p;
    const int qb[2] = {qt0 * 64, qt1 * 64};

    // Q fragments for both parts x both heads (resident; qa L2-hot)
    bf16x8 aq[2][2][2];
#pragma unroll
    for (int part = 0; part < 2; part++)
#pragma unroll
        for (int hd = 0; hd < 2; hd++)
#pragma unroll
            for (int c = 0; c < 2; c++)
                aq[part][hd][c] = *(const bf16x8*)&qa[(size_t)(h0 + hd) * (S * D)
                                    + (size_t)qb[part] * D + (w * 16 + col) * 64 + c * 32 + quad * 8];

    float l_run[2][2][4] = {};
    float4v o_acc[2][2][4];
#pragma unroll
    for (int part = 0; part < 2; part++)
#pragma unroll
        for (int hd = 0; hd < 2; hd++)
#pragma unroll
            for (int dg = 0; dg < 4; dg++) o_acc[part][hd][dg] = zero4;

    for (int kt = 0; kt <= qt1; kt++) {
        const int kb = kt * 64;
        // K/V fragments once per kt; reused by up to 4 chains
        bf16x8 bk[4][2], bv[4][2];
#pragma unroll
        for (int n16 = 0; n16 < 4; n16++) {
            const unsigned short* kr = &Kg[(size_t)(kb + n16 * 16 + col) * 64 + quad * 8];
            bk[n16][0] = *(const bf16x8*)kr;
            bk[n16][1] = *(const bf16x8*)(kr + 32);
        }
#pragma unroll
        for (int dg = 0; dg < 4; dg++) {
            const unsigned short* vr = &Vg[(size_t)(dg * 16 + col) * S + kb + quad * 8];
            bv[dg][0] = *(const bf16x8*)vr;
            bv[dg][1] = *(const bf16x8*)(vr + 32);
        }

#pragma unroll
        for (int part = 0; part < 2; part++) {
            const int qtp = part ? qt1 : qt0;
            if (kt > qtp) continue;            // wave-uniform: part0 done past its diagonal
#pragma unroll
            for (int hd = 0; hd < 2; hd++) {
                float4v sc[4];
                __builtin_amdgcn_s_setprio(1);
#pragma unroll
                for (int n16 = 0; n16 < 4; n16++) {
                    float4v a = __builtin_amdgcn_mfma_f32_16x16x32_bf16(aq[part][hd][0], bk[n16][0], zero4, 0, 0, 0);
                    sc[n16] = __builtin_amdgcn_mfma_f32_16x16x32_bf16(aq[part][hd][1], bk[n16][1], a, 0, 0, 0);
                }
                __builtin_amdgcn_s_setprio(0);
                if (kt == qtp) {
                    // diagonal tile only: mask key_local > qrow_local
#pragma unroll
                    for (int n16 = 0; n16 < 4; n16++) {
                        int keyl = n16 * 16 + col;
#pragma unroll
                        for (int r = 0; r < 4; r++) {
                            int qrl = w * 16 + quad * 4 + r;
                            sc[n16][r] = (keyl <= qrl) ? sc[n16][r] : -1e30f;
                        }
                    }
                }
#pragma unroll
                for (int n16 = 0; n16 < 4; n16++)
#pragma unroll
                    for (int r = 0; r < 4; r++) {
                        float pr = __builtin_amdgcn_exp2f(sc[n16][r]);
                        sc[n16][r] = pr;
                        l_run[part][hd][r] += pr;
                        Ps[w * 1152 + (quad * 4 + r) * 72 + n16 * 16 + col] = f2b_n(pr);
                    }
                bf16x8 ap[2];
#pragma unroll
                for (int c = 0; c < 2; c++)
                    ap[c] = *(const bf16x8*)&Ps[w * 1152 + col * 72 + c * 32 + quad * 8];
                __builtin_amdgcn_s_setprio(1);
#pragma unroll
                for (int dg = 0; dg < 4; dg++) {
                    float4v t = __builtin_amdgcn_mfma_f32_16x16x32_bf16(ap[0], bv[dg][0], o_acc[part][hd][dg], 0, 0, 0);
                    o_acc[part][hd][dg] = __builtin_amdgcn_mfma_f32_16x16x32_bf16(ap[1], bv[dg][1], t, 0, 0, 0);
                }
                __builtin_amdgcn_s_setprio(0);
            }
        }
    }

#pragma unroll
    for (int part = 0; part < 2; part++)
#pragma unroll
        for (int hd = 0; hd < 2; hd++) {
            const int hcol = ((h0 + hd) & 63) * 64;
#pragma unroll
            for (int r = 0; r < 4; r++) {
                float lsum = l_run[part][hd][r];
#pragma unroll
                for (int off = 1; off < 16; off <<= 1) lsum += __shfl_xor(lsum, off);
                float inv = 1.f / lsum;
                int grow = b * S + qb[part] + w * 16 + quad * 4 + r;
#pragma unroll
                for (int dg = 0; dg < 4; dg++)
                    out[(size_t)grow * H + hcol + dg * 16 + col] = f2b_n(o_acc[part][hd][dg][r] * inv);
            }
        }
}

extern "C" void kernel_launch(void* const* d_in, const int* in_sizes, int n_in,
                              void* d_out, int out_size, void* d_ws, size_t ws_size,
                              hipStream_t stream) {
    const float* hs   = (const float*)d_in[0];
    // d_in[1] alibi, d_in[2] attention_mask: unused by reference (zeros)
    const float* cosb = (const float*)d_in[3];
    const float* sinb = (const float*)d_in[4];
    const float* wq   = (const float*)d_in[5];
    const float* wk   = (const float*)d_in[6];
    const float* wv   = (const float*)d_in[7];
    const float* wd   = (const float*)d_in[8];

    char* p = (char*)d_ws;
    auto alloc = [&](size_t bytes) { char* r = p; p += (bytes + 255) & ~(size_t)255; return r; };
    unsigned short* wqkv_b = (unsigned short*)alloc((size_t)NQKV * H * 2);
    unsigned short* wd_b   = (unsigned short*)alloc((size_t)H * H * 2);
    unsigned short* qa     = (unsigned short*)alloc((size_t)BB * NH * S * D * 2);
    unsigned short* ka     = (unsigned short*)alloc((size_t)BB * NKV * S * D * 2);
    unsigned short* vt     = (unsigned short*)alloc((size_t)BB * NKV * S * D * 2);
    unsigned short* hs_b   = (unsigned short*)alloc((size_t)MROWS * H * 2);
    unsigned short* ao     = hs_b;  // alias: hs_b consumed by GEMM1 before attn writes ao

    cvt_all<<<4096, 256, 0, stream>>>(hs, wq, wk, wv, wd, hs_b, wqkv_b, wd_b);

    // GEMM1 with fused RoPE+scatter epilogue (writes qa/ka/vt directly)
    gemm_nt<1><<<dim3(NQKV / 128, MROWS / 128), 256, 0, stream>>>(
        hs_b, wqkv_b, nullptr, MROWS, NQKV, H, cosb, sinb, qa, ka, vt);
    attn_kernel<<<dim3(8, 64), 256, 0, stream>>>(qa, ka, vt, ao);
    gemm_nt<0><<<dim3(H / 128, MROWS / 128), 256, 0, stream>>>(
        ao, wd_b, d_out, MROWS, H, H, nullptr, nullptr, nullptr, nullptr, nullptr);
}

// Round 9
// 438.217 us; speedup vs baseline: 1.2096x; 1.0799x over previous
//
#include <hip/hip_runtime.h>
#include <hip/hip_bf16.h>
#include <cstdint>

typedef short short8 __attribute__((ext_vector_type(8)));
typedef __bf16 bf16x8 __attribute__((ext_vector_type(8)));
typedef float float4v __attribute__((ext_vector_type(4)));
typedef float float16v __attribute__((ext_vector_type(16)));

#define NKV 8
#define G 8
#define D 64
#define NH 64
#define BB 2
#define S 1024
#define H 4096
#define MROWS (BB*S)         // 2048
#define NQKV (H + 2*NKV*D)   // 5120

__device__ __forceinline__ unsigned short f2b(float f) {
    union { float f; uint32_t u; } v; v.f = f;
    uint32_t u = v.u;
    uint32_t r = (u + 0x7FFFu + ((u >> 16) & 1u)) >> 16;
    return (unsigned short)r;
}
__device__ __forceinline__ float b2f(unsigned short b) {
    union { float f; uint32_t u; } v; v.u = ((uint32_t)b) << 16;
    return v.f;
}
// native RNE bf16 cast
__device__ __forceinline__ unsigned short f2b_n(float f) {
    union { __bf16 h; unsigned short u; } v; v.h = (__bf16)f;
    return v.u;
}

__device__ __forceinline__ void gload_lds16(const unsigned short* g, unsigned short* l) {
    __builtin_amdgcn_global_load_lds(
        (const __attribute__((address_space(1))) uint32_t*)g,
        (__attribute__((address_space(3))) uint32_t*)l, 16, 0, 0);
}

// ---------------- fused fp32 -> bf16 conversion for all 5 tensors ----------------
__global__ void cvt_all(const float* __restrict__ hs, const float* __restrict__ wq,
                        const float* __restrict__ wk, const float* __restrict__ wv,
                        const float* __restrict__ wd,
                        unsigned short* __restrict__ hs_b, unsigned short* __restrict__ wqkv_b,
                        unsigned short* __restrict__ wd_b) {
    const size_t N0 = (size_t)MROWS * H;      // 8388608  hs
    const size_t N1 = (size_t)H * H;          // 16777216 wq
    const size_t N2 = (size_t)512 * H;        // 2097152  wk
    const size_t N3 = (size_t)512 * H;        // 2097152  wv
    const size_t N4 = (size_t)H * H;          // 16777216 wd
    const size_t total4 = (N0 + N1 + N2 + N3 + N4) / 4;
    size_t i = (size_t)blockIdx.x * blockDim.x + threadIdx.x;
    const size_t stride = (size_t)gridDim.x * blockDim.x;
    for (; i < total4; i += stride) {
        size_t e = i * 4;
        const float* s; unsigned short* d;
        if (e < N0)                { s = hs + e;                  d = hs_b + e; }
        else if (e < N0+N1)        { s = wq + (e-N0);             d = wqkv_b + (e-N0); }
        else if (e < N0+N1+N2)     { s = wk + (e-N0-N1);          d = wqkv_b + N1 + (e-N0-N1); }
        else if (e < N0+N1+N2+N3)  { s = wv + (e-N0-N1-N2);       d = wqkv_b + N1+N2 + (e-N0-N1-N2); }
        else                       { s = wd + (e-N0-N1-N2-N3);    d = wd_b + (e-N0-N1-N2-N3); }
        float4 f = *(const float4*)s;
        ushort4 o;
        o.x = f2b(f.x); o.y = f2b(f.y); o.z = f2b(f.z); o.w = f2b(f.w);
        *(ushort4*)d = o;
    }
}

// ---------------- NT GEMM: C[M,N] = A[M,K] * W[N,K]^T ----------------
// Proven structure: 128x128 tile, BK=32, 4 waves (2x2 of 64x64),
// mfma_f32_32x32x16_bf16 (2x2 of 32x32 per wave), global_load_lds width=16 staging,
// XOR chunk swizzle, pointer-bumped K loop.
// MODE 0: plain fp32 C store (GEMM2).
// MODE 1: fused QKV epilogue (GEMM1) with RoPE; scale folded into Q; V transposed via LDS.
template <int MODE>
__global__ __launch_bounds__(256) void gemm_nt(
    const unsigned short* __restrict__ A, const unsigned short* __restrict__ W,
    void* __restrict__ Cv, int M, int N, int K,
    const float* __restrict__ cosb, const float* __restrict__ sinb,
    unsigned short* __restrict__ qa, unsigned short* __restrict__ ka,
    unsigned short* __restrict__ vt) {
    __shared__ unsigned short sh[17408];  // As | Bs; reused as 128x136 V-transpose tile
    unsigned short* As = sh;
    unsigned short* Bs = sh + 4096;
    const int bm = blockIdx.y * 128, bn = blockIdx.x * 128;
    const int tid = threadIdx.x;
    const int w = tid >> 6, lane = tid & 63;
    const int n32 = lane & 31, khalf = lane >> 5;
    const int wm = (w & 1) * 64, wn = (w >> 1) * 64;

    const int r0 = tid >> 2;
    const int c0 = (tid & 3) ^ ((r0 >> 2) & 3);
    const unsigned short* pA0 = A + (size_t)(bm + r0) * K + c0 * 8;
    const unsigned short* pA1 = A + (size_t)(bm + r0 + 64) * K + c0 * 8;
    const unsigned short* pW0 = W + (size_t)(bn + r0) * K + c0 * 8;
    const unsigned short* pW1 = W + (size_t)(bn + r0 + 64) * K + c0 * 8;
    unsigned short* Asl0 = As + tid * 8;
    unsigned short* Asl1 = As + 2048 + tid * 8;
    unsigned short* Bsl0 = Bs + tid * 8;
    unsigned short* Bsl1 = Bs + 2048 + tid * 8;

    const unsigned short* aP[2][2];
    const unsigned short* bP[2][2];
#pragma unroll
    for (int g = 0; g < 2; g++)
#pragma unroll
        for (int s = 0; s < 2; s++) {
            int cp = ((s << 1) | khalf) ^ ((n32 >> 2) & 3);
            aP[g][s] = &As[(wm + g * 32 + n32) * 32 + cp * 8];
            bP[g][s] = &Bs[(wn + g * 32 + n32) * 32 + cp * 8];
        }

    float16v acc[2][2] = {};

    const int iters = K >> 5;
    for (int it = 0; it < iters; ++it) {
        __syncthreads();
        gload_lds16(pA0, Asl0);
        gload_lds16(pA1, Asl1);
        gload_lds16(pW0, Bsl0);
        gload_lds16(pW1, Bsl1);
        pA0 += 32; pA1 += 32; pW0 += 32; pW1 += 32;
        __syncthreads();
        bf16x8 af[2][2], bf[2][2];
#pragma unroll
        for (int g = 0; g < 2; g++)
#pragma unroll
            for (int s = 0; s < 2; s++) {
                af[g][s] = *(const bf16x8*)aP[g][s];
                bf[g][s] = *(const bf16x8*)bP[g][s];
            }
#pragma unroll
        for (int s = 0; s < 2; s++)
#pragma unroll
            for (int mg = 0; mg < 2; mg++)
#pragma unroll
                for (int ng = 0; ng < 2; ng++)
                    acc[mg][ng] = __builtin_amdgcn_mfma_f32_32x32x16_bf16(
                        af[mg][s], bf[ng][s], acc[mg][ng], 0, 0, 0);
    }

    // C/D layout (verified): col = lane&31, row = (reg&3) + 8*(reg>>2) + 4*(lane>>5)
    if (MODE == 0) {
#pragma unroll
        for (int mg = 0; mg < 2; mg++) {
#pragma unroll
            for (int ng = 0; ng < 2; ng++) {
                int gcol = bn + wn + ng * 32 + n32;
#pragma unroll
                for (int reg = 0; reg < 16; reg++) {
                    int grow = bm + wm + mg * 32 + (reg & 3) + 8 * (reg >> 2) + 4 * khalf;
                    ((float*)Cv)[(size_t)grow * N + gcol] = acc[mg][ng][reg];
                }
            }
        }
    } else {
        const int colbase = bn + wn;  // 64-aligned: one head's d-range per wave
        const float SCQ = 0.125f * 1.44269504089f;
        if (bn < H + 512) {
            // Q or K with fused RoPE (block-uniform branch; per-wave stores coalesced)
#pragma unroll
            for (int mg = 0; mg < 2; mg++) {
#pragma unroll
                for (int reg = 0; reg < 16; reg++) {
                    int grow = bm + wm + mg * 32 + (reg & 3) + 8 * (reg >> 2) + 4 * khalf;
                    int s = grow & 1023, b = grow >> 10;
                    float x0 = acc[mg][0][reg], x1 = acc[mg][1][reg];
                    float c0  = cosb[s * 64 + n32],      sn0 = sinb[s * 64 + n32];
                    float c1  = cosb[s * 64 + 32 + n32], sn1 = sinb[s * 64 + 32 + n32];
                    float y0 = x0 * c0 - x1 * sn0;
                    float y1 = x1 * c1 + x0 * sn1;
                    unsigned short* dp;
                    if (bn < H) {
                        y0 *= SCQ; y1 *= SCQ;   // fold score scale into Q
                        dp = qa + (size_t)(b * 64 + (colbase >> 6)) * (S * D) + s * 64 + n32;
                    } else {
                        dp = ka + (size_t)(b * 8 + ((colbase - H) >> 6)) * (S * D) + s * 64 + n32;
                    }
                    dp[0] = f2b(y0); dp[32] = f2b(y1);
                }
            }
        } else {
            // V block: cooperative 128x128 transpose via LDS, stores coalesced along s
            __syncthreads();   // everyone done with As/Bs (aliased by sh)
#pragma unroll
            for (int mg = 0; mg < 2; mg++)
#pragma unroll
                for (int ng = 0; ng < 2; ng++)
#pragma unroll
                    for (int reg = 0; reg < 16; reg++) {
                        int cl = wn + ng * 32 + n32;   // local col = V's d-within-block
                        int rl = wm + mg * 32 + (reg & 3) + 8 * (reg >> 2) + 4 * khalf;
                        sh[cl * 136 + rl] = f2b(acc[mg][ng][reg]);
                    }
            __syncthreads();
            {
                const int bb = bm >> 10, s0 = bm & 1023;
                const int kv0 = (bn - (H + 512)) >> 6;
                const int cl = tid >> 1, shalf = (tid & 1) * 64;
                const int kv = kv0 + (cl >> 6), dd = cl & 63;
                unsigned short* dstp = vt + (size_t)(bb * 8 + kv) * (D * S)
                                          + (size_t)dd * S + s0 + shalf;
                const unsigned short* srcp = sh + cl * 136 + shalf;
#pragma unroll
                for (int j = 0; j < 8; j++)
                    *(short8*)(dstp + j * 8) = *(const short8*)(srcp + j * 8);
            }
        }
    }
}

// ---------------- Flash attention: kt-outer 4-chain + async LDS double-buffer ----------------
// Round-9: replace per-wave direct global K/V loads (16 x dwordx4, ~200-400cy L2 wait on
// the critical path every tile) with cooperative async staging: 4 global_load_lds per
// thread into KV[2] (double buffer), counted vmcnt(4) so next tile's loads stay in
// flight across the barrier (raw s_barrier -- __syncthreads would drain vmcnt(0)).
// LDS rows are 128B => XOR chunk swizzle slot = chunk ^ (row&7), applied inverse on the
// global source (gload_lds dest stays linear) and on the ds_read addresses (2-way, free).
// Compute identical to round-8: 4 chains (2 q-parts x 2 heads) per staged tile.
__global__ __launch_bounds__(256, 2) void attn_kernel(
    const unsigned short* __restrict__ qa, const unsigned short* __restrict__ ka,
    const unsigned short* __restrict__ vt, unsigned short* __restrict__ out) {
    __shared__ unsigned short KV[2][8192];       // [buf][K 64x64 | V^T 64x64], swizzled
    __shared__ unsigned short Ps[4 * 16 * 72];   // wave-private P round-trip
    const int p = blockIdx.x;
    const int yy = blockIdx.y;
    const int b = yy >> 5, kvh = (yy >> 2) & 7, gp = yy & 3;
    const int h0 = b * 64 + kvh * 8 + gp * 2;
    const int tid = threadIdx.x, w = tid >> 6, lane = tid & 63;
    const int col = lane & 15, quad = lane >> 4;
    const unsigned short* Kg = ka + (size_t)(b * NKV + kvh) * (S * D);
    const unsigned short* Vg = vt + (size_t)(b * NKV + kvh) * (D * S);
    float4v zero4 = {0.f, 0.f, 0.f, 0.f};

    // staging map: thread t -> row r=t>>3 (and r+32), chunk t&7; source chunk
    // inverse-swizzled so LDS[row][slot] = global[row][slot ^ (row&7)]
    const int sr = tid >> 3;
    const int scs = ((tid & 7) ^ (sr & 7)) * 8;

#define ATTN_STAGE(BUF, KB) { \
    gload_lds16(Kg + (size_t)((KB) + sr) * 64 + scs,      &KV[BUF][tid * 8]); \
    gload_lds16(Kg + (size_t)((KB) + sr + 32) * 64 + scs, &KV[BUF][2048 + tid * 8]); \
    gload_lds16(Vg + (size_t)sr * S + (KB) + scs,         &KV[BUF][4096 + tid * 8]); \
    gload_lds16(Vg + (size_t)(sr + 32) * S + (KB) + scs,  &KV[BUF][6144 + tid * 8]); }

    const int qt0 = p, qt1 = 15 - p;
    const int qb[2] = {qt0 * 64, qt1 * 64};

    // Q fragments for both parts x both heads (resident; qa L2-hot)
    bf16x8 aq[2][2][2];
#pragma unroll
    for (int part = 0; part < 2; part++)
#pragma unroll
        for (int hd = 0; hd < 2; hd++)
#pragma unroll
            for (int c = 0; c < 2; c++)
                aq[part][hd][c] = *(const bf16x8*)&qa[(size_t)(h0 + hd) * (S * D)
                                    + (size_t)qb[part] * D + (w * 16 + col) * 64 + c * 32 + quad * 8];

    float l_run[2][2][4] = {};
    float4v o_acc[2][2][4];
#pragma unroll
    for (int part = 0; part < 2; part++)
#pragma unroll
        for (int hd = 0; hd < 2; hd++)
#pragma unroll
            for (int dg = 0; dg < 4; dg++) o_acc[part][hd][dg] = zero4;

    // prologue: stage tile 0, full drain
    ATTN_STAGE(0, 0)
    asm volatile("s_waitcnt vmcnt(0)" ::: "memory");
    __builtin_amdgcn_s_barrier();

    for (int kt = 0; kt <= qt1; kt++) {
        const int cur = kt & 1;
        // issue next tile's stage (clamped on last iter: keeps vmcnt uniform; writes
        // land in the buffer not read this iteration)
        const int knext = ((kt < qt1) ? kt + 1 : qt1) * 64;
        ATTN_STAGE(cur ^ 1, knext)
        // drain current tile's 4 loads; next tile's 4 stay in flight across the barrier
        asm volatile("s_waitcnt vmcnt(4)" ::: "memory");
        __builtin_amdgcn_s_barrier();
        __builtin_amdgcn_sched_barrier(0);

        // K/V fragments from LDS once per tile; reused by up to 4 chains
        const unsigned short* Kl = KV[cur];
        const unsigned short* Vl = KV[cur] + 4096;
        bf16x8 bk[4][2], bv[4][2];
#pragma unroll
        for (int n16 = 0; n16 < 4; n16++) {
            const int R = n16 * 16 + col, x = R & 7;
            bk[n16][0] = *(const bf16x8*)&Kl[R * 64 + (quad ^ x) * 8];
            bk[n16][1] = *(const bf16x8*)&Kl[R * 64 + ((quad + 4) ^ x) * 8];
        }
#pragma unroll
        for (int dg = 0; dg < 4; dg++) {
            const int R = dg * 16 + col, x = R & 7;
            bv[dg][0] = *(const bf16x8*)&Vl[R * 64 + (quad ^ x) * 8];
            bv[dg][1] = *(const bf16x8*)&Vl[R * 64 + ((quad + 4) ^ x) * 8];
        }

#pragma unroll
        for (int part = 0; part < 2; part++) {
            const int qtp = part ? qt1 : qt0;
            if (kt > qtp) continue;            // wave-uniform: part0 done past its diagonal
#pragma unroll
            for (int hd = 0; hd < 2; hd++) {
                float4v sc[4];
                __builtin_amdgcn_s_setprio(1);
#pragma unroll
                for (int n16 = 0; n16 < 4; n16++) {
                    float4v a = __builtin_amdgcn_mfma_f32_16x16x32_bf16(aq[part][hd][0], bk[n16][0], zero4, 0, 0, 0);
                    sc[n16] = __builtin_amdgcn_mfma_f32_16x16x32_bf16(aq[part][hd][1], bk[n16][1], a, 0, 0, 0);
                }
                __builtin_amdgcn_s_setprio(0);
                if (kt == qtp) {
                    // diagonal tile only: mask key_local > qrow_local
#pragma unroll
                    for (int n16 = 0; n16 < 4; n16++) {
                        int keyl = n16 * 16 + col;
#pragma unroll
                        for (int r = 0; r < 4; r++) {
                            int qrl = w * 16 + quad * 4 + r;
                            sc[n16][r] = (keyl <= qrl) ? sc[n16][r] : -1e30f;
                        }
                    }
                }
#pragma unroll
                for (int n16 = 0; n16 < 4; n16++)
#pragma unroll
                    for (int r = 0; r < 4; r++) {
                        float pr = __builtin_amdgcn_exp2f(sc[n16][r]);
                        sc[n16][r] = pr;
                        l_run[part][hd][r] += pr;
                        Ps[w * 1152 + (quad * 4 + r) * 72 + n16 * 16 + col] = f2b_n(pr);
                    }
                bf16x8 ap[2];
#pragma unroll
                for (int c = 0; c < 2; c++)
                    ap[c] = *(const bf16x8*)&Ps[w * 1152 + col * 72 + c * 32 + quad * 8];
                __builtin_amdgcn_s_setprio(1);
#pragma unroll
                for (int dg = 0; dg < 4; dg++) {
                    float4v t = __builtin_amdgcn_mfma_f32_16x16x32_bf16(ap[0], bv[dg][0], o_acc[part][hd][dg], 0, 0, 0);
                    o_acc[part][hd][dg] = __builtin_amdgcn_mfma_f32_16x16x32_bf16(ap[1], bv[dg][1], t, 0, 0, 0);
                }
                __builtin_amdgcn_s_setprio(0);
            }
        }
        // close compute on buf cur before next iter's stage overwrites it
        __builtin_amdgcn_sched_barrier(0);
        __builtin_amdgcn_s_barrier();
    }

#pragma unroll
    for (int part = 0; part < 2; part++)
#pragma unroll
        for (int hd = 0; hd < 2; hd++) {
            const int hcol = ((h0 + hd) & 63) * 64;
#pragma unroll
            for (int r = 0; r < 4; r++) {
                float lsum = l_run[part][hd][r];
#pragma unroll
                for (int off = 1; off < 16; off <<= 1) lsum += __shfl_xor(lsum, off);
                float inv = 1.f / lsum;
                int grow = b * S + qb[part] + w * 16 + quad * 4 + r;
#pragma unroll
                for (int dg = 0; dg < 4; dg++)
                    out[(size_t)grow * H + hcol + dg * 16 + col] = f2b_n(o_acc[part][hd][dg][r] * inv);
            }
        }
#undef ATTN_STAGE
}

extern "C" void kernel_launch(void* const* d_in, const int* in_sizes, int n_in,
                              void* d_out, int out_size, void* d_ws, size_t ws_size,
                              hipStream_t stream) {
    const float* hs   = (const float*)d_in[0];
    // d_in[1] alibi, d_in[2] attention_mask: unused by reference (zeros)
    const float* cosb = (const float*)d_in[3];
    const float* sinb = (const float*)d_in[4];
    const float* wq   = (const float*)d_in[5];
    const float* wk   = (const float*)d_in[6];
    const float* wv   = (const float*)d_in[7];
    const float* wd   = (const float*)d_in[8];

    char* p = (char*)d_ws;
    auto alloc = [&](size_t bytes) { char* r = p; p += (bytes + 255) & ~(size_t)255; return r; };
    unsigned short* wqkv_b = (unsigned short*)alloc((size_t)NQKV * H * 2);
    unsigned short* wd_b   = (unsigned short*)alloc((size_t)H * H * 2);
    unsigned short* qa     = (unsigned short*)alloc((size_t)BB * NH * S * D * 2);
    unsigned short* ka     = (unsigned short*)alloc((size_t)BB * NKV * S * D * 2);
    unsigned short* vt     = (unsigned short*)alloc((size_t)BB * NKV * S * D * 2);
    unsigned short* hs_b   = (unsigned short*)alloc((size_t)MROWS * H * 2);
    unsigned short* ao     = hs_b;  // alias: hs_b consumed by GEMM1 before attn writes ao

    cvt_all<<<4096, 256, 0, stream>>>(hs, wq, wk, wv, wd, hs_b, wqkv_b, wd_b);

    // GEMM1 with fused RoPE+scatter epilogue (writes qa/ka/vt directly)
    gemm_nt<1><<<dim3(NQKV / 128, MROWS / 128), 256, 0, stream>>>(
        hs_b, wqkv_b, nullptr, MROWS, NQKV, H, cosb, sinb, qa, ka, vt);
    attn_kernel<<<dim3(8, 64), 256, 0, stream>>>(qa, ka, vt, ao);
    gemm_nt<0><<<dim3(H / 128, MROWS / 128), 256, 0, stream>>>(
        ao, wd_b, d_out, MROWS, H, H, nullptr, nullptr, nullptr, nullptr, nullptr);
}